// Round 2
// 375.800 us; speedup vs baseline: 1.0042x; 1.0042x over previous
//
#include <hip/hip_runtime.h>
#include <hip/hip_bf16.h>

// Problem constants
constexpr int B  = 4;
constexpr int S  = 2048;
constexpr int H  = 1024;
constexpr int NH = 16;
constexpr int HD = 64;
constexpr int P  = 64;
constexpr int INTER = 2048;
constexpr int M  = B * S;   // 8192 rows

typedef __bf16  bf16x8   __attribute__((ext_vector_type(8)));
typedef float   floatx4  __attribute__((ext_vector_type(4)));
typedef float   floatx16 __attribute__((ext_vector_type(16)));

#define AS1 __attribute__((address_space(1)))
#define AS3 __attribute__((address_space(3)))
#define VMCNT(n) asm volatile("s_waitcnt vmcnt(" #n ")" ::: "memory")

// ---------------------------------------------------------------------------
// LayerNorm: one block per row of 1024, 256 threads, float4/thread, bf16 out
// ---------------------------------------------------------------------------
__global__ __launch_bounds__(256) void mc_ln_kernel(
    const float* __restrict__ x, const float* __restrict__ g,
    const float* __restrict__ b, __bf16* __restrict__ y)
{
    int row = blockIdx.x;
    const float4* xr = (const float4*)(x + (size_t)row * H);
    float4 v = xr[threadIdx.x];
    float s  = v.x + v.y + v.z + v.w;
    float s2 = v.x*v.x + v.y*v.y + v.z*v.z + v.w*v.w;
    #pragma unroll
    for (int off = 32; off > 0; off >>= 1) {
        s  += __shfl_down(s,  off);
        s2 += __shfl_down(s2, off);
    }
    __shared__ float ws1[4], ws2[4];
    __shared__ float smu, srv;
    int lane = threadIdx.x & 63, wid = threadIdx.x >> 6;
    if (lane == 0) { ws1[wid] = s; ws2[wid] = s2; }
    __syncthreads();
    if (threadIdx.x == 0) {
        float t1 = ws1[0] + ws1[1] + ws1[2] + ws1[3];
        float t2 = ws2[0] + ws2[1] + ws2[2] + ws2[3];
        float mu  = t1 * (1.0f / H);
        float var = t2 * (1.0f / H) - mu * mu;
        smu = mu;
        srv = rsqrtf(var + 1e-12f);
    }
    __syncthreads();
    float mu = smu, rv = srv;
    float4 gv = ((const float4*)g)[threadIdx.x];
    float4 bv = ((const float4*)b)[threadIdx.x];
    union { ushort4 u; __bf16 h[4]; } pk;
    pk.h[0] = (__bf16)((v.x - mu) * rv * gv.x + bv.x);
    pk.h[1] = (__bf16)((v.y - mu) * rv * gv.y + bv.y);
    pk.h[2] = (__bf16)((v.z - mu) * rv * gv.z + bv.z);
    pk.h[3] = (__bf16)((v.w - mu) * rv * gv.w + bv.w);
    ((ushort4*)(y + (size_t)row * H))[threadIdx.x] = pk.u;
}

// ---------------------------------------------------------------------------
// Transpose (+optional momentum update) fp32 [R][C] -> bf16 [C][R]
// ---------------------------------------------------------------------------
__global__ __launch_bounds__(256) void mc_trans_kernel(
    const float* __restrict__ src0, const float* __restrict__ mom0,
    __bf16* __restrict__ dst0,
    const float* __restrict__ src1, const float* __restrict__ mom1,
    __bf16* __restrict__ dst1,
    int Rdim, int Cdim, int do_upd)
{
    const float* src = blockIdx.z ? src1 : src0;
    const float* mom = blockIdx.z ? mom1 : mom0;
    __bf16*      dst = blockIdx.z ? dst1 : dst0;
    __shared__ float ts[32][33];
    int c0 = blockIdx.x * 32, r0 = blockIdx.y * 32;
    int tx = threadIdx.x & 31, ty0 = threadIdx.x >> 5;
    #pragma unroll
    for (int i = 0; i < 4; i++) {
        int r = ty0 + i * 8;
        size_t idx = (size_t)(r0 + r) * Cdim + c0 + tx;
        float v = src[idx];
        if (do_upd) v = 0.99f * v + 0.9f * mom[idx];
        ts[r][tx] = v;
    }
    __syncthreads();
    #pragma unroll
    for (int i = 0; i < 4; i++) {
        int r = ty0 + i * 8;
        dst[(size_t)(c0 + r) * Rdim + r0 + tx] = (__bf16)ts[tx][r];
    }
}

// fused bias updates: nb1[INTER], nb2[H]
__global__ void mc_upd_kernel(const float* __restrict__ b1, const float* __restrict__ mb1,
                              float* __restrict__ nb1,
                              const float* __restrict__ b2, const float* __restrict__ mb2,
                              float* __restrict__ nb2)
{
    int i = blockIdx.x * blockDim.x + threadIdx.x;
    if (i < INTER) nb1[i] = 0.99f * b1[i] + 0.9f * mb1[i];
    else {
        int j = i - INTER;
        if (j < H) nb2[j] = 0.99f * b2[j] + 0.9f * mb2[j];
    }
}

// ---------------------------------------------------------------------------
// Pipelined bf16 MFMA GEMM: C[M,N] = A[M,K] @ Bt[N,K]^T  (+bias/res/relu)
//
// BM=256, BN=256 or 128, BK=32. 512 threads = 8 waves (2M x 4N), per-wave
// output 128 x (BN/4), 32x32x16 MFMA (4 m-frags x NF n-frags x 2 ksteps).
//
// Pipeline: 4 LDS slots per matrix, prefetch distance 3, counted vmcnt
// (never 0 in steady state), ONE raw s_barrier per K-tile.
// Race-freedom: iter t computes slot t%4 and stages tile t+3 into slot
// (t-1)%4; any wave at iter t has passed the end-of-(t-1) barrier, which it
// can only reach after its slot-(t-1)%4 frag reads retired (lgkmcnt precedes
// the MFMAs that precede the barrier).
//
// LDS layout (per slot, per matrix): off(row,c) = row*64B + (c^((row>>1)&3))*16B.
// Realized with LINEAR global_load_lds dest + inverse-swizzled GLOBAL source;
// frag reads apply the same XOR -> every consecutive 8 lanes of a half-wave
// cover all 8 16B-granules of a 128B line (32 banks, conflict-free), and
// staging stays 64B-contiguous per 4 lanes.
// ---------------------------------------------------------------------------
template<int BN>
__global__ __launch_bounds__(512, 2) void mc_gemm_p(
    const __bf16* __restrict__ A, const __bf16* __restrict__ Bt,
    const float* __restrict__ bias,
    const float* __restrict__ resF, const __bf16* __restrict__ resB,
    float* __restrict__ outF, __bf16* __restrict__ outB,
    int Ndim, int Kdim, int do_relu)
{
    static_assert(BN == 128 || BN == 256, "BN");
    constexpr int NF    = BN / 128;        // n-frags per wave (32-wide each)
    constexpr int BSLOT = BN * 32;         // elems per B slot
    __shared__ alignas(128) __bf16 lds[32768 + 4 * BSLOT];  // A: 4x8192 elems

    int tid  = threadIdx.x;
    int lane = tid & 63;
    int w    = tid >> 6;
    int wm   = w >> 2;                     // 0..1
    int wn   = w & 3;                      // 0..3
    int r5   = lane & 31;
    int half = lane >> 5;

    // XCD-aware bijective swizzle (nwg=256, nbx=8, nby=32): XCD k owns a
    // contiguous 4-row band of m-blocks across all 8 n-blocks.
    int gid  = blockIdx.x;
    int wgid = (gid & 7) * 32 + (gid >> 3);
    int by   = wgid >> 3, bx = wgid & 7;
    int m0   = by * 256,  n0 = bx * BN;

    const int NT = Kdim >> 5;              // K-tiles of 32

    // --- precomputed staging sources (inverse-swizzled global addresses) ---
    int f0 = tid, f1 = 512 + tid;
    int r0s = f0 >> 2, c0s = (f0 & 3) ^ ((r0s >> 1) & 3);
    int r1s = f1 >> 2, c1s = (f1 & 3) ^ ((r1s >> 1) & 3);
    const __bf16* aS0 = A  + (size_t)(m0 + r0s) * Kdim + c0s * 8;
    const __bf16* aS1 = A  + (size_t)(m0 + r1s) * Kdim + c1s * 8;
    const __bf16* bS0 = Bt + (size_t)(n0 + r0s) * Kdim + c0s * 8;
    const __bf16* bS1 = Bt + (size_t)(n0 + r1s) * Kdim + c1s * 8;

    auto stage = [&](int t, int s) {
        int k0 = t * 32;
        __builtin_amdgcn_global_load_lds((const AS1 void*)(aS0 + k0),
            (AS3 void*)(lds + s * 8192 + f0 * 8), 16, 0, 0);
        __builtin_amdgcn_global_load_lds((const AS1 void*)(aS1 + k0),
            (AS3 void*)(lds + s * 8192 + f1 * 8), 16, 0, 0);
        __builtin_amdgcn_global_load_lds((const AS1 void*)(bS0 + k0),
            (AS3 void*)(lds + 32768 + s * BSLOT + f0 * 8), 16, 0, 0);
        if constexpr (BN == 256)
            __builtin_amdgcn_global_load_lds((const AS1 void*)(bS1 + k0),
                (AS3 void*)(lds + 32768 + s * BSLOT + f1 * 8), 16, 0, 0);
    };

    // --- loop-invariant fragment offsets (elements) ---
    int aoff[2][4], boff[2][NF];
    #pragma unroll
    for (int ks = 0; ks < 2; ks++) {
        int c = 2 * ks + half;
        #pragma unroll
        for (int i = 0; i < 4; i++) {
            int row = wm * 128 + i * 32 + r5;
            aoff[ks][i] = row * 32 + ((c ^ ((row >> 1) & 3)) * 8);
        }
        #pragma unroll
        for (int j = 0; j < NF; j++) {
            int row = wn * (BN / 4) + j * 32 + r5;
            boff[ks][j] = row * 32 + ((c ^ ((row >> 1) & 3)) * 8);
        }
    }

    // --- prologue: stage tiles 0..2, wait for tile 0 (2 tiles in flight) ---
    stage(0, 0); stage(1, 1); stage(2, 2);
    if constexpr (BN == 256) VMCNT(8); else VMCNT(6);
    __builtin_amdgcn_s_barrier();
    __builtin_amdgcn_sched_barrier(0);

    floatx16 acc[4][NF] = {};

    for (int t = 0; t < NT; t++) {
        int s = t & 3;
        if (t + 3 < NT) stage(t + 3, (t + 3) & 3);

        const __bf16* Ab = lds + s * 8192;
        const __bf16* Bb = lds + 32768 + s * BSLOT;
        #pragma unroll
        for (int ks = 0; ks < 2; ks++) {
            bf16x8 af[4], bfr[NF];
            #pragma unroll
            for (int i = 0; i < 4; i++)
                af[i] = *(const bf16x8*)&Ab[aoff[ks][i]];
            #pragma unroll
            for (int j = 0; j < NF; j++)
                bfr[j] = *(const bf16x8*)&Bb[boff[ks][j]];
            __builtin_amdgcn_s_setprio(1);
            #pragma unroll
            for (int i = 0; i < 4; i++)
                #pragma unroll
                for (int j = 0; j < NF; j++)
                    acc[i][j] = __builtin_amdgcn_mfma_f32_32x32x16_bf16(
                        af[i], bfr[j], acc[i][j], 0, 0, 0);
            __builtin_amdgcn_s_setprio(0);
        }

        if (t + 1 < NT) {
            // need tile t+1 landed; allow tiles t+2,t+3 (if issued) in flight
            if (t + 3 < NT)      { if constexpr (BN == 256) VMCNT(8); else VMCNT(6); }
            else if (t + 2 < NT) { if constexpr (BN == 256) VMCNT(4); else VMCNT(3); }
            else                 VMCNT(0);
            __builtin_amdgcn_s_barrier();
            __builtin_amdgcn_sched_barrier(0);
        }
    }

    // epilogue: col = lane&31 (+32*j), row = (reg&3) + 8*(reg>>2) + 4*half
    #pragma unroll
    for (int i = 0; i < 4; i++) {
        #pragma unroll
        for (int j = 0; j < NF; j++) {
            int col = n0 + wn * (BN / 4) + j * 32 + r5;
            float bv = bias ? bias[col] : 0.0f;
            #pragma unroll
            for (int reg = 0; reg < 16; reg++) {
                int row = m0 + wm * 128 + i * 32 + (reg & 3) + 8 * (reg >> 2) + 4 * half;
                size_t idx = (size_t)row * Ndim + col;
                float v = acc[i][j][reg] + bv;
                if (resF)    v += resF[idx];
                if (resB)    v += (float)resB[idx];
                if (do_relu) v  = fmaxf(v, 0.0f);
                if (outF) outF[idx] = v;
                if (outB) outB[idx] = (__bf16)v;
            }
        }
    }
}

// ---------------------------------------------------------------------------
// Fused q-projection + persistent attention (round-5, verified).
// Block = 128 rows x 2 heads.
// ---------------------------------------------------------------------------
constexpr int QLD = 136;
constexpr int KLD = 72;

__global__ __launch_bounds__(256) void mc_qattn(
    const __bf16* __restrict__ A,      // normb [M,H]
    const __bf16* __restrict__ Bt,     // Wqt [H,H]
    const float* __restrict__ bq,
    const float* __restrict__ pv,
    __bf16* __restrict__ attn)
{
    __shared__ __bf16 Qs[128 * QLD];
    __shared__ union {
        struct { __bf16 As[128 * 64]; __bf16 Bs[128 * 64]; } g;
        struct { __bf16 Ks[64 * KLD]; __bf16 KTs[64 * KLD];
                 __bf16 Ps[128 * KLD]; } a;
    } u;

    int tid  = threadIdx.x;
    int lane = tid & 63;
    int w    = tid >> 6;
    int l16  = lane & 15;
    int quad = lane >> 4;
    int sw   = l16 & 7;

    int hp = blockIdx.x;
    int m0 = blockIdx.y * 128;
    int n0 = hp * 128;

    int wm = (w >> 1) * 64, wn = (w & 1) * 64;
    floatx4 acc[4][4] = {};
    for (int k0 = 0; k0 < H; k0 += 64) {
        #pragma unroll
        for (int t = 0; t < 4; t++) {
            int f = t * 256 + tid;
            int r = f >> 3, c = (f & 7) ^ (r & 7);
            __builtin_amdgcn_global_load_lds(
                (const AS1 void*)(A + (size_t)(m0 + r) * H + k0 + c * 8),
                (AS3 void*)(u.g.As + f * 8), 16, 0, 0);
        }
        #pragma unroll
        for (int t = 0; t < 4; t++) {
            int f = t * 256 + tid;
            int r = f >> 3, c = (f & 7) ^ (r & 7);
            __builtin_amdgcn_global_load_lds(
                (const AS1 void*)(Bt + (size_t)(n0 + r) * H + k0 + c * 8),
                (AS3 void*)(u.g.Bs + f * 8), 16, 0, 0);
        }
        __syncthreads();
        #pragma unroll
        for (int ks = 0; ks < 2; ks++) {
            int cq = ((ks << 2) | quad) ^ sw;
            bf16x8 af[4], bfr[4];
            #pragma unroll
            for (int i = 0; i < 4; i++)
                af[i] = *(const bf16x8*)&u.g.As[(wm + i * 16 + l16) * 64 + cq * 8];
            #pragma unroll
            for (int j = 0; j < 4; j++)
                bfr[j] = *(const bf16x8*)&u.g.Bs[(wn + j * 16 + l16) * 64 + cq * 8];
            #pragma unroll
            for (int i = 0; i < 4; i++)
                #pragma unroll
                for (int j = 0; j < 4; j++)
                    acc[i][j] = __builtin_amdgcn_mfma_f32_16x16x32_bf16(
                        af[i], bfr[j], acc[i][j], 0, 0, 0);
        }
        __syncthreads();
    }

    #pragma unroll
    for (int i = 0; i < 4; i++) {
        #pragma unroll
        for (int j = 0; j < 4; j++) {
            int col = wn + j * 16 + l16;
            float bv = bq[n0 + col];
            #pragma unroll
            for (int r = 0; r < 4; r++) {
                int row = wm + i * 16 + quad * 4 + r;
                Qs[row * QLD + col] = (__bf16)(acc[i][j][r] + bv);
            }
        }
    }

    int rbase = w * 32;
    #pragma unroll
    for (int hh = 0; hh < 2; hh++) {
        int gh = 2 * hp + hh;
        __syncthreads();
        for (int i = tid; i < 64 * 64; i += 256) {
            int p = i >> 6, d = i & 63;
            __bf16 bv = (__bf16)pv[(size_t)p * H + gh * 64 + d];
            u.a.Ks[p * KLD + d]  = bv;
            u.a.KTs[d * KLD + p] = bv;
        }
        __syncthreads();

        floatx4 sc[2][4] = {};
        #pragma unroll
        for (int ks = 0; ks < 2; ks++) {
            bf16x8 aq[2], bk[4];
            #pragma unroll
            for (int i = 0; i < 2; i++)
                aq[i] = *(const bf16x8*)&Qs[(rbase + i * 16 + l16) * QLD +
                                            hh * 64 + ks * 32 + quad * 8];
            #pragma unroll
            for (int j = 0; j < 4; j++)
                bk[j] = *(const bf16x8*)&u.a.Ks[(j * 16 + l16) * KLD + ks * 32 + quad * 8];
            #pragma unroll
            for (int i = 0; i < 2; i++)
                #pragma unroll
                for (int j = 0; j < 4; j++)
                    sc[i][j] = __builtin_amdgcn_mfma_f32_16x16x32_bf16(
                        aq[i], bk[j], sc[i][j], 0, 0, 0);
        }

        #pragma unroll
        for (int i = 0; i < 2; i++) {
            #pragma unroll
            for (int r = 0; r < 4; r++) {
                float v0 = sc[i][0][r] * 0.125f;
                float v1 = sc[i][1][r] * 0.125f;
                float v2 = sc[i][2][r] * 0.125f;
                float v3 = sc[i][3][r] * 0.125f;
                float mx = fmaxf(fmaxf(v0, v1), fmaxf(v2, v3));
                #pragma unroll
                for (int off = 8; off > 0; off >>= 1) mx = fmaxf(mx, __shfl_xor(mx, off));
                float e0 = __expf(v0 - mx), e1 = __expf(v1 - mx);
                float e2 = __expf(v2 - mx), e3 = __expf(v3 - mx);
                float sm = e0 + e1 + e2 + e3;
                #pragma unroll
                for (int off = 8; off > 0; off >>= 1) sm += __shfl_xor(sm, off);
                float inv = __frcp_rn(sm);
                int row = rbase + i * 16 + quad * 4 + r;
                u.a.Ps[row * KLD +  0 + l16] = (__bf16)(e0 * inv);
                u.a.Ps[row * KLD + 16 + l16] = (__bf16)(e1 * inv);
                u.a.Ps[row * KLD + 32 + l16] = (__bf16)(e2 * inv);
                u.a.Ps[row * KLD + 48 + l16] = (__bf16)(e3 * inv);
            }
        }
        __syncthreads();

        floatx4 ov[2][4] = {};
        #pragma unroll
        for (int ks = 0; ks < 2; ks++) {
            bf16x8 ap[2], bkt[4];
            #pragma unroll
            for (int i = 0; i < 2; i++)
                ap[i] = *(const bf16x8*)&u.a.Ps[(rbase + i * 16 + l16) * KLD + ks * 32 + quad * 8];
            #pragma unroll
            for (int j = 0; j < 4; j++)
                bkt[j] = *(const bf16x8*)&u.a.KTs[(j * 16 + l16) * KLD + ks * 32 + quad * 8];
            #pragma unroll
            for (int i = 0; i < 2; i++)
                #pragma unroll
                for (int j = 0; j < 4; j++)
                    ov[i][j] = __builtin_amdgcn_mfma_f32_16x16x32_bf16(
                        ap[i], bkt[j], ov[i][j], 0, 0, 0);
        }

        #pragma unroll
        for (int i = 0; i < 2; i++) {
            #pragma unroll
            for (int j = 0; j < 4; j++) {
                int col = j * 16 + l16;
                #pragma unroll
                for (int r = 0; r < 4; r++) {
                    int row = rbase + i * 16 + quad * 4 + r;
                    attn[(size_t)(m0 + row) * H + gh * 64 + col] = (__bf16)ov[i][j][r];
                }
            }
        }
    }
}

// ---------------------------------------------------------------------------
extern "C" void kernel_launch(void* const* d_in, const int* in_sizes, int n_in,
                              void* d_out, int out_size, void* d_ws, size_t ws_size,
                              hipStream_t stream)
{
    const float* hidden = (const float*)d_in[0];
    const float* pv   = (const float*)d_in[3];
    const float* Wq   = (const float*)d_in[4];
    const float* bq   = (const float*)d_in[5];
    const float* Wo   = (const float*)d_in[6];
    const float* bo   = (const float*)d_in[7];
    const float* ln_g = (const float*)d_in[8];
    const float* ln_b = (const float*)d_in[9];
    const float* W1   = (const float*)d_in[10];
    const float* b1   = (const float*)d_in[11];
    const float* W2   = (const float*)d_in[12];
    const float* b2   = (const float*)d_in[13];
    const float* mW1  = (const float*)d_in[14];
    const float* mb1  = (const float*)d_in[15];
    const float* mW2  = (const float*)d_in[16];
    const float* mb2  = (const float*)d_in[17];

    float* out = (float*)d_out;
    char*  wsb = (char*)d_ws;

    constexpr size_t MB = 1024 * 1024;
    __bf16* normb  = (__bf16*)(wsb);               // 16 MB  [M,H]
    __bf16* attnb  = (__bf16*)(wsb + 16  * MB);    // 16 MB  [M,H]
    __bf16* out1b  = (__bf16*)(wsb + 32  * MB);    // 16 MB  [M,H]
    __bf16* hb     = (__bf16*)(wsb + 48  * MB);    // 32 MB  [M,INTER]
    __bf16* Wqt    = (__bf16*)(wsb + 80  * MB);    // 2 MB   [H,H]
    __bf16* Wot    = (__bf16*)(wsb + 82  * MB);    // 2 MB   [H,H]
    __bf16* W1t    = (__bf16*)(wsb + 84  * MB);    // 4 MB   [INTER,H]
    __bf16* W2t    = (__bf16*)(wsb + 88  * MB);    // 4 MB   [H,INTER]
    float*  nb1    = (float*) (wsb + 92  * MB);    // 8 KB
    float*  nb2    = (float*) (wsb + 92  * MB + 8192);

    // weight prep
    mc_trans_kernel<<<dim3(32, 32, 2), 256, 0, stream>>>(
        Wq, nullptr, Wqt, Wo, nullptr, Wot, H, H, 0);
    mc_trans_kernel<<<dim3(64, 32, 1), 256, 0, stream>>>(
        W1, mW1, W1t, nullptr, nullptr, nullptr, H, INTER, 1);
    mc_trans_kernel<<<dim3(32, 64, 1), 256, 0, stream>>>(
        W2, mW2, W2t, nullptr, nullptr, nullptr, INTER, H, 1);
    mc_upd_kernel<<<(INTER + H + 255) / 256, 256, 0, stream>>>(b1, mb1, nb1, b2, mb2, nb2);

    // 1) hs_norm = LN(hidden) -> bf16
    mc_ln_kernel<<<M, 256, 0, stream>>>(hidden, ln_g, ln_b, normb);

    // 2+3) fused q-projection + attention -> attnb
    mc_qattn<<<dim3(NH / 2, M / 128), 256, 0, stream>>>(normb, Wqt, bq, pv, attnb);

    // 4) out1 = hidden + attnb @ Wo + bo  -> bf16 out1b   (N=1024, K=1024)
    mc_gemm_p<128><<<256, 512, 0, stream>>>(attnb, Wot, bo, hidden, nullptr,
                                            nullptr, out1b, H, H, 0);

    // 5) h = relu(out1b @ W1t^T + nb1) -> bf16             (N=2048, K=1024)
    mc_gemm_p<256><<<256, 512, 0, stream>>>(out1b, W1t, nb1, nullptr, nullptr,
                                            nullptr, hb, INTER, H, 1);

    // 6) out = out1b + hb @ W2t^T + nb2 -> fp32 d_out      (N=1024, K=2048)
    mc_gemm_p<128><<<256, 512, 0, stream>>>(hb, W2t, nb2, nullptr, out1b,
                                            out, nullptr, H, INTER, 0);
}

// Round 3
// 358.097 us; speedup vs baseline: 1.0539x; 1.0494x over previous
//
#include <hip/hip_runtime.h>
#include <hip/hip_bf16.h>

// Problem constants
constexpr int B  = 4;
constexpr int S  = 2048;
constexpr int H  = 1024;
constexpr int NH = 16;
constexpr int HD = 64;
constexpr int P  = 64;
constexpr int INTER = 2048;
constexpr int M  = B * S;   // 8192 rows

typedef __bf16  bf16x8   __attribute__((ext_vector_type(8)));
typedef float   floatx4  __attribute__((ext_vector_type(4)));
typedef float   floatx16 __attribute__((ext_vector_type(16)));

#define AS1 __attribute__((address_space(1)))
#define AS3 __attribute__((address_space(3)))
#define VMCNT(n) asm volatile("s_waitcnt vmcnt(" #n ")" ::: "memory")

// ---------------------------------------------------------------------------
// LayerNorm: one block per row of 1024, 256 threads, float4/thread, bf16 out
// ---------------------------------------------------------------------------
__global__ __launch_bounds__(256) void mc_ln_kernel(
    const float* __restrict__ x, const float* __restrict__ g,
    const float* __restrict__ b, __bf16* __restrict__ y)
{
    int row = blockIdx.x;
    const float4* xr = (const float4*)(x + (size_t)row * H);
    float4 v = xr[threadIdx.x];
    float s  = v.x + v.y + v.z + v.w;
    float s2 = v.x*v.x + v.y*v.y + v.z*v.z + v.w*v.w;
    #pragma unroll
    for (int off = 32; off > 0; off >>= 1) {
        s  += __shfl_down(s,  off);
        s2 += __shfl_down(s2, off);
    }
    __shared__ float ws1[4], ws2[4];
    __shared__ float smu, srv;
    int lane = threadIdx.x & 63, wid = threadIdx.x >> 6;
    if (lane == 0) { ws1[wid] = s; ws2[wid] = s2; }
    __syncthreads();
    if (threadIdx.x == 0) {
        float t1 = ws1[0] + ws1[1] + ws1[2] + ws1[3];
        float t2 = ws2[0] + ws2[1] + ws2[2] + ws2[3];
        float mu  = t1 * (1.0f / H);
        float var = t2 * (1.0f / H) - mu * mu;
        smu = mu;
        srv = rsqrtf(var + 1e-12f);
    }
    __syncthreads();
    float mu = smu, rv = srv;
    float4 gv = ((const float4*)g)[threadIdx.x];
    float4 bv = ((const float4*)b)[threadIdx.x];
    union { ushort4 u; __bf16 h[4]; } pk;
    pk.h[0] = (__bf16)((v.x - mu) * rv * gv.x + bv.x);
    pk.h[1] = (__bf16)((v.y - mu) * rv * gv.y + bv.y);
    pk.h[2] = (__bf16)((v.z - mu) * rv * gv.z + bv.z);
    pk.h[3] = (__bf16)((v.w - mu) * rv * gv.w + bv.w);
    ((ushort4*)(y + (size_t)row * H))[threadIdx.x] = pk.u;
}

// ---------------------------------------------------------------------------
// Transpose (+optional momentum update) fp32 [R][C] -> bf16 [C][R]
// ---------------------------------------------------------------------------
__global__ __launch_bounds__(256) void mc_trans_kernel(
    const float* __restrict__ src0, const float* __restrict__ mom0,
    __bf16* __restrict__ dst0,
    const float* __restrict__ src1, const float* __restrict__ mom1,
    __bf16* __restrict__ dst1,
    int Rdim, int Cdim, int do_upd)
{
    const float* src = blockIdx.z ? src1 : src0;
    const float* mom = blockIdx.z ? mom1 : mom0;
    __bf16*      dst = blockIdx.z ? dst1 : dst0;
    __shared__ float ts[32][33];
    int c0 = blockIdx.x * 32, r0 = blockIdx.y * 32;
    int tx = threadIdx.x & 31, ty0 = threadIdx.x >> 5;
    #pragma unroll
    for (int i = 0; i < 4; i++) {
        int r = ty0 + i * 8;
        size_t idx = (size_t)(r0 + r) * Cdim + c0 + tx;
        float v = src[idx];
        if (do_upd) v = 0.99f * v + 0.9f * mom[idx];
        ts[r][tx] = v;
    }
    __syncthreads();
    #pragma unroll
    for (int i = 0; i < 4; i++) {
        int r = ty0 + i * 8;
        dst[(size_t)(c0 + r) * Rdim + r0 + tx] = (__bf16)ts[tx][r];
    }
}

// fused bias updates: nb1[INTER], nb2[H]
__global__ void mc_upd_kernel(const float* __restrict__ b1, const float* __restrict__ mb1,
                              float* __restrict__ nb1,
                              const float* __restrict__ b2, const float* __restrict__ mb2,
                              float* __restrict__ nb2)
{
    int i = blockIdx.x * blockDim.x + threadIdx.x;
    if (i < INTER) nb1[i] = 0.99f * b1[i] + 0.9f * mb1[i];
    else {
        int j = i - INTER;
        if (j < H) nb2[j] = 0.99f * b2[j] + 0.9f * mb2[j];
    }
}

// ---------------------------------------------------------------------------
// Pipelined bf16 MFMA GEMM: C[M,N] = A[M,K] @ Bt[N,K]^T  (+bias/res/relu)
//
// BM=256, BK=32, 512 threads = 8 waves.  16x16x32 MFMA for fat per-wave
// reuse (round-3 change: LDS-traffic/MFMA cut from 1.25KB to 0.375-0.5KB):
//   BN=256: waves 2Mx4N, wave tile 128x64 = 8x4 frags -> 12 reads / 32 MFMA
//   BN=128: waves 4Mx2N, wave tile  64x64 = 4x4 frags ->  8 reads / 16 MFMA
//
// Pipeline (verified round 2): 4 LDS slots, prefetch distance 3, counted
// vmcnt (never 0 in steady state), ONE raw s_barrier per K-tile.
// Race-freedom: iter t computes slot t%4 and stages tile t+3 into slot
// (t-1)%4; any wave at iter t has passed the end-of-(t-1) barrier, which it
// can only reach after its slot-(t-1)%4 frag reads retired (lgkmcnt precedes
// the MFMAs that precede the barrier).
//
// LDS layout (per slot, per matrix): off(row,c) = row*64B + (c^((row>>1)&3))*16B.
// Linear global_load_lds dest + inverse-swizzled GLOBAL source; frag reads
// apply the same XOR -> each 8 consecutive lanes cover all 32 banks.
// ---------------------------------------------------------------------------
template<int BN, int WMW>
__global__ __launch_bounds__(512, 2) void mc_gemm_p(
    const __bf16* __restrict__ A, const __bf16* __restrict__ Bt,
    const float* __restrict__ bias,
    const float* __restrict__ resF, const __bf16* __restrict__ resB,
    float* __restrict__ outF, __bf16* __restrict__ outB,
    int Ndim, int Kdim, int do_relu)
{
    static_assert(BN == 128 || BN == 256, "BN");
    constexpr int WNW = 8 / WMW;           // waves along N
    constexpr int WR  = 256 / WMW;         // rows per wave tile
    constexpr int WC  = BN / WNW;          // cols per wave tile
    constexpr int FM  = WR / 16;           // m-frags per wave
    constexpr int FN  = WC / 16;           // n-frags per wave
    constexpr int ASLOT = 256 * 32;        // elems per A slot (16 KB)
    constexpr int BSLOT = BN * 32;         // elems per B slot
    __shared__ __bf16 lds[4 * ASLOT + 4 * BSLOT];

    int tid  = threadIdx.x;
    int lane = tid & 63;
    int w    = tid >> 6;
    int wm   = w / WNW;
    int wn   = w % WNW;
    int l16  = lane & 15;
    int quad = lane >> 4;

    // XCD-aware bijective swizzle (nwg=256, nbx=8, nby=32): XCD k owns a
    // contiguous 4-row band of m-blocks across all 8 n-blocks.
    int gid  = blockIdx.x;
    int wgid = (gid & 7) * 32 + (gid >> 3);
    int by   = wgid >> 3, bx = wgid & 7;
    int m0   = by * 256,  n0 = bx * BN;

    const int NT = Kdim >> 5;              // K-tiles of 32

    // --- staging sources (inverse-swizzled global addresses) ---
    int f0 = tid, f1 = 512 + tid;
    int r0s = f0 >> 2, c0s = (f0 & 3) ^ ((r0s >> 1) & 3);
    int r1s = f1 >> 2, c1s = (f1 & 3) ^ ((r1s >> 1) & 3);
    const __bf16* aS0 = A  + (size_t)(m0 + r0s) * Kdim + c0s * 8;
    const __bf16* aS1 = A  + (size_t)(m0 + r1s) * Kdim + c1s * 8;
    const __bf16* bS0 = Bt + (size_t)(n0 + r0s) * Kdim + c0s * 8;
    const __bf16* bS1 = Bt + (size_t)(n0 + r1s) * Kdim + c1s * 8;

    auto stage = [&](int t, int s) {
        int k0 = t * 32;
        __builtin_amdgcn_global_load_lds((const AS1 void*)(aS0 + k0),
            (AS3 void*)(lds + s * ASLOT + f0 * 8), 16, 0, 0);
        __builtin_amdgcn_global_load_lds((const AS1 void*)(aS1 + k0),
            (AS3 void*)(lds + s * ASLOT + f1 * 8), 16, 0, 0);
        __builtin_amdgcn_global_load_lds((const AS1 void*)(bS0 + k0),
            (AS3 void*)(lds + 4 * ASLOT + s * BSLOT + f0 * 8), 16, 0, 0);
        if constexpr (BN == 256)
            __builtin_amdgcn_global_load_lds((const AS1 void*)(bS1 + k0),
                (AS3 void*)(lds + 4 * ASLOT + s * BSLOT + f1 * 8), 16, 0, 0);
    };

    // --- loop-invariant fragment offsets (elements) ---
    // 16x16x32 A/B frag: lane reads 8 elems at row = frag*16 + l16,
    // k-chunk = quad (one 16x16x32 MFMA consumes the whole K=32 tile).
    int aoff[FM], boff[FN];
    #pragma unroll
    for (int i = 0; i < FM; i++) {
        int row = wm * WR + i * 16 + l16;
        aoff[i] = row * 32 + ((quad ^ ((row >> 1) & 3)) * 8);
    }
    #pragma unroll
    for (int j = 0; j < FN; j++) {
        int row = wn * WC + j * 16 + l16;
        boff[j] = row * 32 + ((quad ^ ((row >> 1) & 3)) * 8);
    }

    // --- prologue: stage tiles 0..2, wait for tile 0 (2 tiles in flight) ---
    stage(0, 0); stage(1, 1); stage(2, 2);
    if constexpr (BN == 256) VMCNT(8); else VMCNT(6);
    __builtin_amdgcn_s_barrier();
    __builtin_amdgcn_sched_barrier(0);

    floatx4 acc[FM][FN] = {};

    for (int t = 0; t < NT; t++) {
        int s = t & 3;
        if (t + 3 < NT) stage(t + 3, (t + 3) & 3);

        const __bf16* Ab = lds + s * ASLOT;
        const __bf16* Bb = lds + 4 * ASLOT + s * BSLOT;
        bf16x8 af[FM], bfr[FN];
        #pragma unroll
        for (int i = 0; i < FM; i++)
            af[i] = *(const bf16x8*)&Ab[aoff[i]];
        #pragma unroll
        for (int j = 0; j < FN; j++)
            bfr[j] = *(const bf16x8*)&Bb[boff[j]];
        __builtin_amdgcn_s_setprio(1);
        #pragma unroll
        for (int i = 0; i < FM; i++)
            #pragma unroll
            for (int j = 0; j < FN; j++)
                acc[i][j] = __builtin_amdgcn_mfma_f32_16x16x32_bf16(
                    af[i], bfr[j], acc[i][j], 0, 0, 0);
        __builtin_amdgcn_s_setprio(0);

        if (t + 1 < NT) {
            // need tile t+1 landed; allow tiles t+2,t+3 (if issued) in flight
            if (t + 3 < NT)      { if constexpr (BN == 256) VMCNT(8); else VMCNT(6); }
            else if (t + 2 < NT) { if constexpr (BN == 256) VMCNT(4); else VMCNT(3); }
            else                 VMCNT(0);
            __builtin_amdgcn_s_barrier();
            __builtin_amdgcn_sched_barrier(0);
        }
    }

    // epilogue: col = l16 side, row = quad*4 + reg  (same mapping as mc_qattn)
    #pragma unroll
    for (int i = 0; i < FM; i++) {
        #pragma unroll
        for (int j = 0; j < FN; j++) {
            int col = n0 + wn * WC + j * 16 + l16;
            float bv = bias ? bias[col] : 0.0f;
            #pragma unroll
            for (int r = 0; r < 4; r++) {
                int row = m0 + wm * WR + i * 16 + quad * 4 + r;
                size_t idx = (size_t)row * Ndim + col;
                float v = acc[i][j][r] + bv;
                if (resF)    v += resF[idx];
                if (resB)    v += (float)resB[idx];
                if (do_relu) v  = fmaxf(v, 0.0f);
                if (outF) outF[idx] = v;
                if (outB) outB[idx] = (__bf16)v;
            }
        }
    }
}

// ---------------------------------------------------------------------------
// Fused q-projection + persistent attention (round-5, verified).
// Block = 128 rows x 2 heads.
// ---------------------------------------------------------------------------
constexpr int QLD = 136;
constexpr int KLD = 72;

__global__ __launch_bounds__(256) void mc_qattn(
    const __bf16* __restrict__ A,      // normb [M,H]
    const __bf16* __restrict__ Bt,     // Wqt [H,H]
    const float* __restrict__ bq,
    const float* __restrict__ pv,
    __bf16* __restrict__ attn)
{
    __shared__ __bf16 Qs[128 * QLD];
    __shared__ union {
        struct { __bf16 As[128 * 64]; __bf16 Bs[128 * 64]; } g;
        struct { __bf16 Ks[64 * KLD]; __bf16 KTs[64 * KLD];
                 __bf16 Ps[128 * KLD]; } a;
    } u;

    int tid  = threadIdx.x;
    int lane = tid & 63;
    int w    = tid >> 6;
    int l16  = lane & 15;
    int quad = lane >> 4;
    int sw   = l16 & 7;

    int hp = blockIdx.x;
    int m0 = blockIdx.y * 128;
    int n0 = hp * 128;

    int wm = (w >> 1) * 64, wn = (w & 1) * 64;
    floatx4 acc[4][4] = {};
    for (int k0 = 0; k0 < H; k0 += 64) {
        #pragma unroll
        for (int t = 0; t < 4; t++) {
            int f = t * 256 + tid;
            int r = f >> 3, c = (f & 7) ^ (r & 7);
            __builtin_amdgcn_global_load_lds(
                (const AS1 void*)(A + (size_t)(m0 + r) * H + k0 + c * 8),
                (AS3 void*)(u.g.As + f * 8), 16, 0, 0);
        }
        #pragma unroll
        for (int t = 0; t < 4; t++) {
            int f = t * 256 + tid;
            int r = f >> 3, c = (f & 7) ^ (r & 7);
            __builtin_amdgcn_global_load_lds(
                (const AS1 void*)(Bt + (size_t)(n0 + r) * H + k0 + c * 8),
                (AS3 void*)(u.g.Bs + f * 8), 16, 0, 0);
        }
        __syncthreads();
        #pragma unroll
        for (int ks = 0; ks < 2; ks++) {
            int cq = ((ks << 2) | quad) ^ sw;
            bf16x8 af[4], bfr[4];
            #pragma unroll
            for (int i = 0; i < 4; i++)
                af[i] = *(const bf16x8*)&u.g.As[(wm + i * 16 + l16) * 64 + cq * 8];
            #pragma unroll
            for (int j = 0; j < 4; j++)
                bfr[j] = *(const bf16x8*)&u.g.Bs[(wn + j * 16 + l16) * 64 + cq * 8];
            #pragma unroll
            for (int i = 0; i < 4; i++)
                #pragma unroll
                for (int j = 0; j < 4; j++)
                    acc[i][j] = __builtin_amdgcn_mfma_f32_16x16x32_bf16(
                        af[i], bfr[j], acc[i][j], 0, 0, 0);
        }
        __syncthreads();
    }

    #pragma unroll
    for (int i = 0; i < 4; i++) {
        #pragma unroll
        for (int j = 0; j < 4; j++) {
            int col = wn + j * 16 + l16;
            float bv = bq[n0 + col];
            #pragma unroll
            for (int r = 0; r < 4; r++) {
                int row = wm + i * 16 + quad * 4 + r;
                Qs[row * QLD + col] = (__bf16)(acc[i][j][r] + bv);
            }
        }
    }

    int rbase = w * 32;
    #pragma unroll
    for (int hh = 0; hh < 2; hh++) {
        int gh = 2 * hp + hh;
        __syncthreads();
        for (int i = tid; i < 64 * 64; i += 256) {
            int p = i >> 6, d = i & 63;
            __bf16 bv = (__bf16)pv[(size_t)p * H + gh * 64 + d];
            u.a.Ks[p * KLD + d]  = bv;
            u.a.KTs[d * KLD + p] = bv;
        }
        __syncthreads();

        floatx4 sc[2][4] = {};
        #pragma unroll
        for (int ks = 0; ks < 2; ks++) {
            bf16x8 aq[2], bk[4];
            #pragma unroll
            for (int i = 0; i < 2; i++)
                aq[i] = *(const bf16x8*)&Qs[(rbase + i * 16 + l16) * QLD +
                                            hh * 64 + ks * 32 + quad * 8];
            #pragma unroll
            for (int j = 0; j < 4; j++)
                bk[j] = *(const bf16x8*)&u.a.Ks[(j * 16 + l16) * KLD + ks * 32 + quad * 8];
            #pragma unroll
            for (int i = 0; i < 2; i++)
                #pragma unroll
                for (int j = 0; j < 4; j++)
                    sc[i][j] = __builtin_amdgcn_mfma_f32_16x16x32_bf16(
                        aq[i], bk[j], sc[i][j], 0, 0, 0);
        }

        #pragma unroll
        for (int i = 0; i < 2; i++) {
            #pragma unroll
            for (int r = 0; r < 4; r++) {
                float v0 = sc[i][0][r] * 0.125f;
                float v1 = sc[i][1][r] * 0.125f;
                float v2 = sc[i][2][r] * 0.125f;
                float v3 = sc[i][3][r] * 0.125f;
                float mx = fmaxf(fmaxf(v0, v1), fmaxf(v2, v3));
                #pragma unroll
                for (int off = 8; off > 0; off >>= 1) mx = fmaxf(mx, __shfl_xor(mx, off));
                float e0 = __expf(v0 - mx), e1 = __expf(v1 - mx);
                float e2 = __expf(v2 - mx), e3 = __expf(v3 - mx);
                float sm = e0 + e1 + e2 + e3;
                #pragma unroll
                for (int off = 8; off > 0; off >>= 1) sm += __shfl_xor(sm, off);
                float inv = __frcp_rn(sm);
                int row = rbase + i * 16 + quad * 4 + r;
                u.a.Ps[row * KLD +  0 + l16] = (__bf16)(e0 * inv);
                u.a.Ps[row * KLD + 16 + l16] = (__bf16)(e1 * inv);
                u.a.Ps[row * KLD + 32 + l16] = (__bf16)(e2 * inv);
                u.a.Ps[row * KLD + 48 + l16] = (__bf16)(e3 * inv);
            }
        }
        __syncthreads();

        floatx4 ov[2][4] = {};
        #pragma unroll
        for (int ks = 0; ks < 2; ks++) {
            bf16x8 ap[2], bkt[4];
            #pragma unroll
            for (int i = 0; i < 2; i++)
                ap[i] = *(const bf16x8*)&u.a.Ps[(rbase + i * 16 + l16) * KLD + ks * 32 + quad * 8];
            #pragma unroll
            for (int j = 0; j < 4; j++)
                bkt[j] = *(const bf16x8*)&u.a.KTs[(j * 16 + l16) * KLD + ks * 32 + quad * 8];
            #pragma unroll
            for (int i = 0; i < 2; i++)
                #pragma unroll
                for (int j = 0; j < 4; j++)
                    ov[i][j] = __builtin_amdgcn_mfma_f32_16x16x32_bf16(
                        ap[i], bkt[j], ov[i][j], 0, 0, 0);
        }

        #pragma unroll
        for (int i = 0; i < 2; i++) {
            #pragma unroll
            for (int j = 0; j < 4; j++) {
                int col = j * 16 + l16;
                #pragma unroll
                for (int r = 0; r < 4; r++) {
                    int row = rbase + i * 16 + quad * 4 + r;
                    attn[(size_t)(m0 + row) * H + gh * 64 + col] = (__bf16)ov[i][j][r];
                }
            }
        }
    }
}

// ---------------------------------------------------------------------------
extern "C" void kernel_launch(void* const* d_in, const int* in_sizes, int n_in,
                              void* d_out, int out_size, void* d_ws, size_t ws_size,
                              hipStream_t stream)
{
    const float* hidden = (const float*)d_in[0];
    const float* pv   = (const float*)d_in[3];
    const float* Wq   = (const float*)d_in[4];
    const float* bq   = (const float*)d_in[5];
    const float* Wo   = (const float*)d_in[6];
    const float* bo   = (const float*)d_in[7];
    const float* ln_g = (const float*)d_in[8];
    const float* ln_b = (const float*)d_in[9];
    const float* W1   = (const float*)d_in[10];
    const float* b1   = (const float*)d_in[11];
    const float* W2   = (const float*)d_in[12];
    const float* b2   = (const float*)d_in[13];
    const float* mW1  = (const float*)d_in[14];
    const float* mb1  = (const float*)d_in[15];
    const float* mW2  = (const float*)d_in[16];
    const float* mb2  = (const float*)d_in[17];

    float* out = (float*)d_out;
    char*  wsb = (char*)d_ws;

    constexpr size_t MB = 1024 * 1024;
    __bf16* normb  = (__bf16*)(wsb);               // 16 MB  [M,H]
    __bf16* attnb  = (__bf16*)(wsb + 16  * MB);    // 16 MB  [M,H]
    __bf16* out1b  = (__bf16*)(wsb + 32  * MB);    // 16 MB  [M,H]
    __bf16* hb     = (__bf16*)(wsb + 48  * MB);    // 32 MB  [M,INTER]
    __bf16* Wqt    = (__bf16*)(wsb + 80  * MB);    // 2 MB   [H,H]
    __bf16* Wot    = (__bf16*)(wsb + 82  * MB);    // 2 MB   [H,H]
    __bf16* W1t    = (__bf16*)(wsb + 84  * MB);    // 4 MB   [INTER,H]
    __bf16* W2t    = (__bf16*)(wsb + 88  * MB);    // 4 MB   [H,INTER]
    float*  nb1    = (float*) (wsb + 92  * MB);    // 8 KB
    float*  nb2    = (float*) (wsb + 92  * MB + 8192);

    // weight prep
    mc_trans_kernel<<<dim3(32, 32, 2), 256, 0, stream>>>(
        Wq, nullptr, Wqt, Wo, nullptr, Wot, H, H, 0);
    mc_trans_kernel<<<dim3(64, 32, 1), 256, 0, stream>>>(
        W1, mW1, W1t, nullptr, nullptr, nullptr, H, INTER, 1);
    mc_trans_kernel<<<dim3(32, 64, 1), 256, 0, stream>>>(
        W2, mW2, W2t, nullptr, nullptr, nullptr, INTER, H, 1);
    mc_upd_kernel<<<(INTER + H + 255) / 256, 256, 0, stream>>>(b1, mb1, nb1, b2, mb2, nb2);

    // 1) hs_norm = LN(hidden) -> bf16
    mc_ln_kernel<<<M, 256, 0, stream>>>(hidden, ln_g, ln_b, normb);

    // 2+3) fused q-projection + attention -> attnb
    mc_qattn<<<dim3(NH / 2, M / 128), 256, 0, stream>>>(normb, Wqt, bq, pv, attnb);

    // 4) out1 = hidden + attnb @ Wo + bo  -> bf16 out1b   (N=1024, K=1024)
    mc_gemm_p<128, 4><<<256, 512, 0, stream>>>(attnb, Wot, bo, hidden, nullptr,
                                               nullptr, out1b, H, H, 0);

    // 5) h = relu(out1b @ W1t^T + nb1) -> bf16             (N=2048, K=1024)
    mc_gemm_p<256, 2><<<256, 512, 0, stream>>>(out1b, W1t, nb1, nullptr, nullptr,
                                               nullptr, hb, INTER, H, 1);

    // 6) out = out1b + hb @ W2t^T + nb2 -> fp32 d_out      (N=1024, K=2048)
    mc_gemm_p<128, 4><<<256, 512, 0, stream>>>(hb, W2t, nb2, nullptr, out1b,
                                               out, nullptr, H, INTER, 0);
}

// Round 4
// 354.087 us; speedup vs baseline: 1.0658x; 1.0113x over previous
//
#include <hip/hip_runtime.h>
#include <hip/hip_bf16.h>

// Problem constants
constexpr int B  = 4;
constexpr int S  = 2048;
constexpr int H  = 1024;
constexpr int NH = 16;
constexpr int HD = 64;
constexpr int P  = 64;
constexpr int INTER = 2048;
constexpr int M  = B * S;   // 8192 rows

typedef __bf16  bf16x8   __attribute__((ext_vector_type(8)));
typedef float   floatx4  __attribute__((ext_vector_type(4)));

#define AS1 __attribute__((address_space(1)))
#define AS3 __attribute__((address_space(3)))
#define VMCNT(n) asm volatile("s_waitcnt vmcnt(" #n ")" ::: "memory")

// ---------------------------------------------------------------------------
// LayerNorm: one block per row of 1024, 256 threads, float4/thread, bf16 out
// ---------------------------------------------------------------------------
__global__ __launch_bounds__(256) void mc_ln_kernel(
    const float* __restrict__ x, const float* __restrict__ g,
    const float* __restrict__ b, __bf16* __restrict__ y)
{
    int row = blockIdx.x;
    const float4* xr = (const float4*)(x + (size_t)row * H);
    float4 v = xr[threadIdx.x];
    float s  = v.x + v.y + v.z + v.w;
    float s2 = v.x*v.x + v.y*v.y + v.z*v.z + v.w*v.w;
    #pragma unroll
    for (int off = 32; off > 0; off >>= 1) {
        s  += __shfl_down(s,  off);
        s2 += __shfl_down(s2, off);
    }
    __shared__ float ws1[4], ws2[4];
    __shared__ float smu, srv;
    int lane = threadIdx.x & 63, wid = threadIdx.x >> 6;
    if (lane == 0) { ws1[wid] = s; ws2[wid] = s2; }
    __syncthreads();
    if (threadIdx.x == 0) {
        float t1 = ws1[0] + ws1[1] + ws1[2] + ws1[3];
        float t2 = ws2[0] + ws2[1] + ws2[2] + ws2[3];
        float mu  = t1 * (1.0f / H);
        float var = t2 * (1.0f / H) - mu * mu;
        smu = mu;
        srv = rsqrtf(var + 1e-12f);
    }
    __syncthreads();
    float mu = smu, rv = srv;
    float4 gv = ((const float4*)g)[threadIdx.x];
    float4 bv = ((const float4*)b)[threadIdx.x];
    union { ushort4 u; __bf16 h[4]; } pk;
    pk.h[0] = (__bf16)((v.x - mu) * rv * gv.x + bv.x);
    pk.h[1] = (__bf16)((v.y - mu) * rv * gv.y + bv.y);
    pk.h[2] = (__bf16)((v.z - mu) * rv * gv.z + bv.z);
    pk.h[3] = (__bf16)((v.w - mu) * rv * gv.w + bv.w);
    ((ushort4*)(y + (size_t)row * H))[threadIdx.x] = pk.u;
}

// ---------------------------------------------------------------------------
// Transpose (+optional momentum update) fp32 [R][C] -> bf16 [C][R]
// ---------------------------------------------------------------------------
__global__ __launch_bounds__(256) void mc_trans_kernel(
    const float* __restrict__ src0, const float* __restrict__ mom0,
    __bf16* __restrict__ dst0,
    const float* __restrict__ src1, const float* __restrict__ mom1,
    __bf16* __restrict__ dst1,
    int Rdim, int Cdim, int do_upd)
{
    const float* src = blockIdx.z ? src1 : src0;
    const float* mom = blockIdx.z ? mom1 : mom0;
    __bf16*      dst = blockIdx.z ? dst1 : dst0;
    __shared__ float ts[32][33];
    int c0 = blockIdx.x * 32, r0 = blockIdx.y * 32;
    int tx = threadIdx.x & 31, ty0 = threadIdx.x >> 5;
    #pragma unroll
    for (int i = 0; i < 4; i++) {
        int r = ty0 + i * 8;
        size_t idx = (size_t)(r0 + r) * Cdim + c0 + tx;
        float v = src[idx];
        if (do_upd) v = 0.99f * v + 0.9f * mom[idx];
        ts[r][tx] = v;
    }
    __syncthreads();
    #pragma unroll
    for (int i = 0; i < 4; i++) {
        int r = ty0 + i * 8;
        dst[(size_t)(c0 + r) * Rdim + r0 + tx] = (__bf16)ts[tx][r];
    }
}

// fused bias updates: nb1[INTER], nb2[H]
__global__ void mc_upd_kernel(const float* __restrict__ b1, const float* __restrict__ mb1,
                              float* __restrict__ nb1,
                              const float* __restrict__ b2, const float* __restrict__ mb2,
                              float* __restrict__ nb2)
{
    int i = blockIdx.x * blockDim.x + threadIdx.x;
    if (i < INTER) nb1[i] = 0.99f * b1[i] + 0.9f * mb1[i];
    else {
        int j = i - INTER;
        if (j < H) nb2[j] = 0.99f * b2[j] + 0.9f * mb2[j];
    }
}

// ---------------------------------------------------------------------------
// 4-phase pipelined bf16 MFMA GEMM: C[M,N] = A[M,K] @ Bt[N,K]^T (+bias/res/relu)
//
// BM=256, BK=64, 512 threads = 8 waves. 16x16x32 MFMA.
//   BN=256: waves 2Mx4N, wave tile 128x64 (FM=8,FN=4), 16 MFMA/phase
//   BN=128: waves 4Mx2N, wave tile  64x64 (FM=4,FN=4),  8 MFMA/phase
//
// K-step split into 4 phases (C-quadrants): P1:(m0,n0) P2:(m0,n1)
// P3:(m1,n1) P4:(m1,n0). Each phase: issue 1 half-tile of NEXT K-step's
// staging, ds-read only this quadrant's new frags, MFMA. Two counted-vmcnt
// gates per K-step (never 0 in steady state):
//   G1 before P1: needs A-h0,B-h0 of cur  -> vmcnt(4) [BN=128: 3]
//   G2 before P2: needs B-h1,A-h1 of cur  -> vmcnt(2)
// Issue order during kt (targets buf (kt+1)&1): P1:A0' P2:B0' P3:B1' P4:A1'.
//
// Race ledger: a wave passes gate-barrier only after all waves' reads of the
// buffer being overwritten retired (their lgkm waits precede the MFMAs that
// precede the barrier); every ds_read is preceded by a gate covering its
// half-tile landing (per-wave vmcnt + barrier -> all waves' slices landed).
//
// Staging half-tiles are re-chunked to match CONSUMPTION halves (per-wave
// row-halves, strided across waves): each gload_lds writes 8 consecutive
// 8-row groups (one per wave, linear dest); global source is per-lane
// inverse-swizzled (c_g = (lane&7) ^ (row&7)) so LDS holds
// off(row,c) = row*128B + (c ^ (row&7))*16B -> frag reads conflict-free.
// ---------------------------------------------------------------------------
template<int BN, int WMW>
__global__ __launch_bounds__(512, 2) void mc_gemm_p(
    const __bf16* __restrict__ A, const __bf16* __restrict__ Bt,
    const float* __restrict__ bias,
    const float* __restrict__ resF, const __bf16* __restrict__ resB,
    float* __restrict__ outF, __bf16* __restrict__ outB,
    int Ndim, int Kdim, int do_relu)
{
    constexpr int WNW = 8 / WMW;           // waves along N
    constexpr int WR  = 256 / WMW;         // rows per wave tile
    constexpr int WC  = BN / WNW;          // cols per wave tile
    constexpr int FM  = WR / 16, FN = WC / 16;
    constexpr int FMH = FM / 2,  FNH = FN / 2;
    constexpr int ABUF = 256 * 64;         // elems per A buffer
    constexpr int BBUF = BN * 64;
    constexpr int BI   = BN / 128;         // gload_lds per B half (1 or 2)
    __shared__ alignas(128) __bf16 lds[2 * ABUF + 2 * BBUF];

    int tid  = threadIdx.x;
    int lane = tid & 63;
    int w    = tid >> 6;
    int wm   = w / WNW;
    int wn   = w % WNW;
    int l16  = lane & 15;
    int quad = lane >> 4;

    // XCD-aware bijective swizzle (nwg=256, 8 n-blocks x 32 m-blocks both BN)
    int gid  = blockIdx.x;
    int wgid = (gid & 7) * 32 + (gid >> 3);
    int by   = wgid >> 3, bx = wgid & 7;
    int m0   = by * 256,  n0 = bx * BN;

    const int NT = Kdim >> 6;              // K-steps of 64

    // --- staging source/dest precompute (consumption-aligned halves) ---
    const __bf16* aSrc[2][2]; int aDst[2][2];
    const __bf16* bSrc[2][2]; int bDst[2][2];
    #pragma unroll
    for (int h = 0; h < 2; h++) {
        #pragma unroll
        for (int p = 0; p < 2; p++) {
            int g = (p * 8 + w) * 8 + (lane >> 3);
            constexpr int HS = WR / 2;
            int r = (g / HS) * WR + h * HS + (g % HS);
            int cg = (lane & 7) ^ (r & 7);
            aSrc[h][p] = A + (size_t)(m0 + r) * Kdim + cg * 8;
            aDst[h][p] = r * 64 + (lane & 7) * 8;
        }
        #pragma unroll
        for (int p = 0; p < BI; p++) {
            int g = (p * 8 + w) * 8 + (lane >> 3);
            constexpr int HS = WC / 2;
            int r = (g / HS) * WC + h * HS + (g % HS);
            int cg = (lane & 7) ^ (r & 7);
            bSrc[h][p] = Bt + (size_t)(n0 + r) * Kdim + cg * 8;
            bDst[h][p] = r * 64 + (lane & 7) * 8;
        }
    }

    auto stageA = [&](int kt, int h) {
        int k0 = kt * 64;
        __bf16* dst = lds + (kt & 1) * ABUF;
        #pragma unroll
        for (int p = 0; p < 2; p++)
            __builtin_amdgcn_global_load_lds((const AS1 void*)(aSrc[h][p] + k0),
                (AS3 void*)(dst + aDst[h][p]), 16, 0, 0);
    };
    auto stageB = [&](int kt, int h) {
        int k0 = kt * 64;
        __bf16* dst = lds + 2 * ABUF + (kt & 1) * BBUF;
        #pragma unroll
        for (int p = 0; p < BI; p++)
            __builtin_amdgcn_global_load_lds((const AS1 void*)(bSrc[h][p] + k0),
                (AS3 void*)(dst + bDst[h][p]), 16, 0, 0);
    };

    // --- loop-invariant fragment offsets (elements) ---
    int aoff[FM][2], boff[FN][2];
    #pragma unroll
    for (int i = 0; i < FM; i++) {
        int row = wm * WR + i * 16 + l16;
        #pragma unroll
        for (int kk = 0; kk < 2; kk++)
            aoff[i][kk] = row * 64 + ((((kk << 2) | quad) ^ (row & 7)) * 8);
    }
    #pragma unroll
    for (int j = 0; j < FN; j++) {
        int row = wn * WC + j * 16 + l16;
        #pragma unroll
        for (int kk = 0; kk < 2; kk++)
            boff[j][kk] = row * 64 + ((((kk << 2) | quad) ^ (row & 7)) * 8);
    }

    // --- prologue: stage K-step 0 fully, drain once ---
    stageA(0, 0); stageB(0, 0); stageB(0, 1); stageA(0, 1);
    VMCNT(0);
    __builtin_amdgcn_s_barrier();
    __builtin_amdgcn_sched_barrier(0);

    floatx4 acc[FM][FN] = {};

    for (int kt = 0; kt < NT; kt++) {
        const __bf16* Ab = lds + (kt & 1) * ABUF;
        const __bf16* Bb = lds + 2 * ABUF + (kt & 1) * BBUF;
        bool pre = (kt + 1 < NT);

        bf16x8 ar[FMH][2], br[FNH][2];

        // G1: need A-h0,B-h0 of kt (kt=0 already drained)
        if (kt) {
            if constexpr (BN == 256) VMCNT(4); else VMCNT(3);
            __builtin_amdgcn_s_barrier();
            __builtin_amdgcn_sched_barrier(0);
        }

        // P1: (m0,n0)
        if (pre) stageA(kt + 1, 0);
        #pragma unroll
        for (int i = 0; i < FMH; i++) {
            ar[i][0] = *(const bf16x8*)&Ab[aoff[i][0]];
            ar[i][1] = *(const bf16x8*)&Ab[aoff[i][1]];
        }
        #pragma unroll
        for (int j = 0; j < FNH; j++) {
            br[j][0] = *(const bf16x8*)&Bb[boff[j][0]];
            br[j][1] = *(const bf16x8*)&Bb[boff[j][1]];
        }
        __builtin_amdgcn_s_setprio(1);
        #pragma unroll
        for (int i = 0; i < FMH; i++)
            #pragma unroll
            for (int j = 0; j < FNH; j++)
                #pragma unroll
                for (int kk = 0; kk < 2; kk++)
                    acc[i][j] = __builtin_amdgcn_mfma_f32_16x16x32_bf16(
                        ar[i][kk], br[j][kk], acc[i][j], 0, 0, 0);
        __builtin_amdgcn_s_setprio(0);
        __builtin_amdgcn_sched_barrier(0);

        // G2: need B-h1,A-h1 of kt
        VMCNT(2);
        __builtin_amdgcn_s_barrier();
        __builtin_amdgcn_sched_barrier(0);

        // P2: (m0,n1)
        if (pre) stageB(kt + 1, 0);
        #pragma unroll
        for (int j = 0; j < FNH; j++) {
            br[j][0] = *(const bf16x8*)&Bb[boff[FNH + j][0]];
            br[j][1] = *(const bf16x8*)&Bb[boff[FNH + j][1]];
        }
        __builtin_amdgcn_s_setprio(1);
        #pragma unroll
        for (int i = 0; i < FMH; i++)
            #pragma unroll
            for (int j = 0; j < FNH; j++)
                #pragma unroll
                for (int kk = 0; kk < 2; kk++)
                    acc[i][FNH + j] = __builtin_amdgcn_mfma_f32_16x16x32_bf16(
                        ar[i][kk], br[j][kk], acc[i][FNH + j], 0, 0, 0);
        __builtin_amdgcn_s_setprio(0);
        __builtin_amdgcn_sched_barrier(0);

        // P3: (m1,n1)
        if (pre) stageB(kt + 1, 1);
        #pragma unroll
        for (int i = 0; i < FMH; i++) {
            ar[i][0] = *(const bf16x8*)&Ab[aoff[FMH + i][0]];
            ar[i][1] = *(const bf16x8*)&Ab[aoff[FMH + i][1]];
        }
        __builtin_amdgcn_s_setprio(1);
        #pragma unroll
        for (int i = 0; i < FMH; i++)
            #pragma unroll
            for (int j = 0; j < FNH; j++)
                #pragma unroll
                for (int kk = 0; kk < 2; kk++)
                    acc[FMH + i][FNH + j] = __builtin_amdgcn_mfma_f32_16x16x32_bf16(
                        ar[i][kk], br[j][kk], acc[FMH + i][FNH + j], 0, 0, 0);
        __builtin_amdgcn_s_setprio(0);
        __builtin_amdgcn_sched_barrier(0);

        // P4: (m1,n0) — B-h0 re-read
        if (pre) stageA(kt + 1, 1);
        #pragma unroll
        for (int j = 0; j < FNH; j++) {
            br[j][0] = *(const bf16x8*)&Bb[boff[j][0]];
            br[j][1] = *(const bf16x8*)&Bb[boff[j][1]];
        }
        __builtin_amdgcn_s_setprio(1);
        #pragma unroll
        for (int i = 0; i < FMH; i++)
            #pragma unroll
            for (int j = 0; j < FNH; j++)
                #pragma unroll
                for (int kk = 0; kk < 2; kk++)
                    acc[FMH + i][j] = __builtin_amdgcn_mfma_f32_16x16x32_bf16(
                        ar[i][kk], br[j][kk], acc[FMH + i][j], 0, 0, 0);
        __builtin_amdgcn_s_setprio(0);
        __builtin_amdgcn_sched_barrier(0);
    }

    // epilogue: col = l16 side, row = quad*4 + reg (16x16x32 C/D mapping)
    #pragma unroll
    for (int i = 0; i < FM; i++) {
        #pragma unroll
        for (int j = 0; j < FN; j++) {
            int col = n0 + wn * WC + j * 16 + l16;
            float bv = bias ? bias[col] : 0.0f;
            #pragma unroll
            for (int r = 0; r < 4; r++) {
                int row = m0 + wm * WR + i * 16 + quad * 4 + r;
                size_t idx = (size_t)row * Ndim + col;
                float v = acc[i][j][r] + bv;
                if (resF)    v += resF[idx];
                if (resB)    v += (float)resB[idx];
                if (do_relu) v  = fmaxf(v, 0.0f);
                if (outF) outF[idx] = v;
                if (outB) outB[idx] = (__bf16)v;
            }
        }
    }
}

// ---------------------------------------------------------------------------
// Fused q-projection + persistent attention (verified).
// Block = 128 rows x 2 heads.
// ---------------------------------------------------------------------------
constexpr int QLD = 136;
constexpr int KLD = 72;

__global__ __launch_bounds__(256) void mc_qattn(
    const __bf16* __restrict__ A,      // normb [M,H]
    const __bf16* __restrict__ Bt,     // Wqt [H,H]
    const float* __restrict__ bq,
    const float* __restrict__ pv,
    __bf16* __restrict__ attn)
{
    __shared__ __bf16 Qs[128 * QLD];
    __shared__ union {
        struct { __bf16 As[128 * 64]; __bf16 Bs[128 * 64]; } g;
        struct { __bf16 Ks[64 * KLD]; __bf16 KTs[64 * KLD];
                 __bf16 Ps[128 * KLD]; } a;
    } u;

    int tid  = threadIdx.x;
    int lane = tid & 63;
    int w    = tid >> 6;
    int l16  = lane & 15;
    int quad = lane >> 4;
    int sw   = l16 & 7;

    int hp = blockIdx.x;
    int m0 = blockIdx.y * 128;
    int n0 = hp * 128;

    int wm = (w >> 1) * 64, wn = (w & 1) * 64;
    floatx4 acc[4][4] = {};
    for (int k0 = 0; k0 < H; k0 += 64) {
        #pragma unroll
        for (int t = 0; t < 4; t++) {
            int f = t * 256 + tid;
            int r = f >> 3, c = (f & 7) ^ (r & 7);
            __builtin_amdgcn_global_load_lds(
                (const AS1 void*)(A + (size_t)(m0 + r) * H + k0 + c * 8),
                (AS3 void*)(u.g.As + f * 8), 16, 0, 0);
        }
        #pragma unroll
        for (int t = 0; t < 4; t++) {
            int f = t * 256 + tid;
            int r = f >> 3, c = (f & 7) ^ (r & 7);
            __builtin_amdgcn_global_load_lds(
                (const AS1 void*)(Bt + (size_t)(n0 + r) * H + k0 + c * 8),
                (AS3 void*)(u.g.Bs + f * 8), 16, 0, 0);
        }
        __syncthreads();
        #pragma unroll
        for (int ks = 0; ks < 2; ks++) {
            int cq = ((ks << 2) | quad) ^ sw;
            bf16x8 af[4], bfr[4];
            #pragma unroll
            for (int i = 0; i < 4; i++)
                af[i] = *(const bf16x8*)&u.g.As[(wm + i * 16 + l16) * 64 + cq * 8];
            #pragma unroll
            for (int j = 0; j < 4; j++)
                bfr[j] = *(const bf16x8*)&u.g.Bs[(wn + j * 16 + l16) * 64 + cq * 8];
            #pragma unroll
            for (int i = 0; i < 4; i++)
                #pragma unroll
                for (int j = 0; j < 4; j++)
                    acc[i][j] = __builtin_amdgcn_mfma_f32_16x16x32_bf16(
                        af[i], bfr[j], acc[i][j], 0, 0, 0);
        }
        __syncthreads();
    }

    #pragma unroll
    for (int i = 0; i < 4; i++) {
        #pragma unroll
        for (int j = 0; j < 4; j++) {
            int col = wn + j * 16 + l16;
            float bv = bq[n0 + col];
            #pragma unroll
            for (int r = 0; r < 4; r++) {
                int row = wm + i * 16 + quad * 4 + r;
                Qs[row * QLD + col] = (__bf16)(acc[i][j][r] + bv);
            }
        }
    }

    int rbase = w * 32;
    #pragma unroll
    for (int hh = 0; hh < 2; hh++) {
        int gh = 2 * hp + hh;
        __syncthreads();
        for (int i = tid; i < 64 * 64; i += 256) {
            int p = i >> 6, d = i & 63;
            __bf16 bv = (__bf16)pv[(size_t)p * H + gh * 64 + d];
            u.a.Ks[p * KLD + d]  = bv;
            u.a.KTs[d * KLD + p] = bv;
        }
        __syncthreads();

        floatx4 sc[2][4] = {};
        #pragma unroll
        for (int ks = 0; ks < 2; ks++) {
            bf16x8 aq[2], bk[4];
            #pragma unroll
            for (int i = 0; i < 2; i++)
                aq[i] = *(const bf16x8*)&Qs[(rbase + i * 16 + l16) * QLD +
                                            hh * 64 + ks * 32 + quad * 8];
            #pragma unroll
            for (int j = 0; j < 4; j++)
                bk[j] = *(const bf16x8*)&u.a.Ks[(j * 16 + l16) * KLD + ks * 32 + quad * 8];
            #pragma unroll
            for (int i = 0; i < 2; i++)
                #pragma unroll
                for (int j = 0; j < 4; j++)
                    sc[i][j] = __builtin_amdgcn_mfma_f32_16x16x32_bf16(
                        aq[i], bk[j], sc[i][j], 0, 0, 0);
        }

        #pragma unroll
        for (int i = 0; i < 2; i++) {
            #pragma unroll
            for (int r = 0; r < 4; r++) {
                float v0 = sc[i][0][r] * 0.125f;
                float v1 = sc[i][1][r] * 0.125f;
                float v2 = sc[i][2][r] * 0.125f;
                float v3 = sc[i][3][r] * 0.125f;
                float mx = fmaxf(fmaxf(v0, v1), fmaxf(v2, v3));
                #pragma unroll
                for (int off = 8; off > 0; off >>= 1) mx = fmaxf(mx, __shfl_xor(mx, off));
                float e0 = __expf(v0 - mx), e1 = __expf(v1 - mx);
                float e2 = __expf(v2 - mx), e3 = __expf(v3 - mx);
                float sm = e0 + e1 + e2 + e3;
                #pragma unroll
                for (int off = 8; off > 0; off >>= 1) sm += __shfl_xor(sm, off);
                float inv = __frcp_rn(sm);
                int row = rbase + i * 16 + quad * 4 + r;
                u.a.Ps[row * KLD +  0 + l16] = (__bf16)(e0 * inv);
                u.a.Ps[row * KLD + 16 + l16] = (__bf16)(e1 * inv);
                u.a.Ps[row * KLD + 32 + l16] = (__bf16)(e2 * inv);
                u.a.Ps[row * KLD + 48 + l16] = (__bf16)(e3 * inv);
            }
        }
        __syncthreads();

        floatx4 ov[2][4] = {};
        #pragma unroll
        for (int ks = 0; ks < 2; ks++) {
            bf16x8 ap[2], bkt[4];
            #pragma unroll
            for (int i = 0; i < 2; i++)
                ap[i] = *(const bf16x8*)&u.a.Ps[(rbase + i * 16 + l16) * KLD + ks * 32 + quad * 8];
            #pragma unroll
            for (int j = 0; j < 4; j++)
                bkt[j] = *(const bf16x8*)&u.a.KTs[(j * 16 + l16) * KLD + ks * 32 + quad * 8];
            #pragma unroll
            for (int i = 0; i < 2; i++)
                #pragma unroll
                for (int j = 0; j < 4; j++)
                    ov[i][j] = __builtin_amdgcn_mfma_f32_16x16x32_bf16(
                        ap[i], bkt[j], ov[i][j], 0, 0, 0);
        }

        #pragma unroll
        for (int i = 0; i < 2; i++) {
            #pragma unroll
            for (int j = 0; j < 4; j++) {
                int col = j * 16 + l16;
                #pragma unroll
                for (int r = 0; r < 4; r++) {
                    int row = rbase + i * 16 + quad * 4 + r;
                    attn[(size_t)(m0 + row) * H + gh * 64 + col] = (__bf16)ov[i][j][r];
                }
            }
        }
    }
}

// ---------------------------------------------------------------------------
extern "C" void kernel_launch(void* const* d_in, const int* in_sizes, int n_in,
                              void* d_out, int out_size, void* d_ws, size_t ws_size,
                              hipStream_t stream)
{
    const float* hidden = (const float*)d_in[0];
    const float* pv   = (const float*)d_in[3];
    const float* Wq   = (const float*)d_in[4];
    const float* bq   = (const float*)d_in[5];
    const float* Wo   = (const float*)d_in[6];
    const float* bo   = (const float*)d_in[7];
    const float* ln_g = (const float*)d_in[8];
    const float* ln_b = (const float*)d_in[9];
    const float* W1   = (const float*)d_in[10];
    const float* b1   = (const float*)d_in[11];
    const float* W2   = (const float*)d_in[12];
    const float* b2   = (const float*)d_in[13];
    const float* mW1  = (const float*)d_in[14];
    const float* mb1  = (const float*)d_in[15];
    const float* mW2  = (const float*)d_in[16];
    const float* mb2  = (const float*)d_in[17];

    float* out = (float*)d_out;
    char*  wsb = (char*)d_ws;

    constexpr size_t MB = 1024 * 1024;
    __bf16* normb  = (__bf16*)(wsb);               // 16 MB  [M,H]
    __bf16* attnb  = (__bf16*)(wsb + 16  * MB);    // 16 MB  [M,H]
    __bf16* out1b  = (__bf16*)(wsb + 32  * MB);    // 16 MB  [M,H]
    __bf16* hb     = (__bf16*)(wsb + 48  * MB);    // 32 MB  [M,INTER]
    __bf16* Wqt    = (__bf16*)(wsb + 80  * MB);    // 2 MB   [H,H]
    __bf16* Wot    = (__bf16*)(wsb + 82  * MB);    // 2 MB   [H,H]
    __bf16* W1t    = (__bf16*)(wsb + 84  * MB);    // 4 MB   [INTER,H]
    __bf16* W2t    = (__bf16*)(wsb + 88  * MB);    // 4 MB   [H,INTER]
    float*  nb1    = (float*) (wsb + 92  * MB);    // 8 KB
    float*  nb2    = (float*) (wsb + 92  * MB + 8192);

    // weight prep
    mc_trans_kernel<<<dim3(32, 32, 2), 256, 0, stream>>>(
        Wq, nullptr, Wqt, Wo, nullptr, Wot, H, H, 0);
    mc_trans_kernel<<<dim3(64, 32, 1), 256, 0, stream>>>(
        W1, mW1, W1t, nullptr, nullptr, nullptr, H, INTER, 1);
    mc_trans_kernel<<<dim3(32, 64, 1), 256, 0, stream>>>(
        W2, mW2, W2t, nullptr, nullptr, nullptr, INTER, H, 1);
    mc_upd_kernel<<<(INTER + H + 255) / 256, 256, 0, stream>>>(b1, mb1, nb1, b2, mb2, nb2);

    // 1) hs_norm = LN(hidden) -> bf16
    mc_ln_kernel<<<M, 256, 0, stream>>>(hidden, ln_g, ln_b, normb);

    // 2+3) fused q-projection + attention -> attnb
    mc_qattn<<<dim3(NH / 2, M / 128), 256, 0, stream>>>(normb, Wqt, bq, pv, attnb);

    // 4) out1 = hidden + attnb @ Wo + bo  -> bf16 out1b   (N=1024, K=1024)
    mc_gemm_p<128, 4><<<256, 512, 0, stream>>>(attnb, Wot, bo, hidden, nullptr,
                                               nullptr, out1b, H, H, 0);

    // 5) h = relu(out1b @ W1t^T + nb1) -> bf16             (N=2048, K=1024)
    mc_gemm_p<256, 2><<<256, 512, 0, stream>>>(out1b, W1t, nb1, nullptr, nullptr,
                                               nullptr, hb, INTER, H, 1);

    // 6) out = out1b + hb @ W2t^T + nb2 -> fp32 d_out      (N=1024, K=2048)
    mc_gemm_p<128, 4><<<256, 512, 0, stream>>>(hb, W2t, nb2, nullptr, out1b,
                                               out, nullptr, H, INTER, 0);
}